// Round 17
// baseline (243.263 us; speedup 1.0000x reference)
//
#include <hip/hip_runtime.h>

// B=8, N=2048, C=512. Flash attention + fp16 MFMA pipeline.
// r17: attn wave-pair D-split: pair owns 32 q; wave dh handles D-half.
// Partial QK^T per D-half (qf 64 VGPR), partials exchanged via dbuf LDS
// S-buffer (+add -> full scores, identical across pair), PV on own D-half
// (accO 128 VGPR). Per-wave LDS bytes/iter: 32KB -> 22KB at same q rate.
// Triple-K/double-G counted-vmcnt schedule (r12); barriers add lgkmcnt(0)
// for the S-exchange ds_writes. Everything else frozen from r16.
// ws: [0]=OA [1]=h [2]=l [3]=gT [4]=OB [5]=Wt(2MB)+ml(256KB)

typedef __attribute__((ext_vector_type(4))) float f32x4;
typedef __attribute__((ext_vector_type(8))) short s16x8;      // fp16 bit-patterns
typedef __attribute__((ext_vector_type(4))) short s16x4;
typedef __attribute__((ext_vector_type(8))) _Float16 f16x8;   // MFMA operands
typedef __attribute__((ext_vector_type(4))) _Float16 f16x4;
typedef __attribute__((ext_vector_type(2))) unsigned u32x2;

typedef unsigned int u32;
typedef __attribute__((address_space(1))) const u32 gu32;
typedef __attribute__((address_space(3))) u32 lu32;

__device__ __forceinline__ void gload16(const short* g, short* l) {
  __builtin_amdgcn_global_load_lds((gu32*)g, (lu32*)l, 16, 0, 0);
}

__device__ __forceinline__ short f2h(float f) {
  _Float16 h = (_Float16)f;
  return __builtin_bit_cast(short, h);
}

__device__ __forceinline__ unsigned pk2h(float a, float b) {
  return __builtin_bit_cast(unsigned, __builtin_amdgcn_cvt_pkrtz(a, b));
}

#define MFMA(a, b, c) __builtin_amdgcn_mfma_f32_16x16x32_f16(a, b, c, 0, 0, 0)
#define MFMA16(a, b, c) __builtin_amdgcn_mfma_f32_16x16x16f16(a, b, c, 0, 0, 0)

#define BAR_KEEP2()                                          \
  do {                                                       \
    asm volatile("s_waitcnt vmcnt(2)" ::: "memory");         \
    __builtin_amdgcn_s_barrier();                            \
    __builtin_amdgcn_sched_barrier(0);                       \
  } while (0)
#define BAR_KEEP2_L()                                        \
  do {                                                       \
    asm volatile("s_waitcnt vmcnt(2) lgkmcnt(0)" ::: "memory"); \
    __builtin_amdgcn_s_barrier();                            \
    __builtin_amdgcn_sched_barrier(0);                       \
  } while (0)
#define BAR_KEEP4_L()                                        \
  do {                                                       \
    asm volatile("s_waitcnt vmcnt(4) lgkmcnt(0)" ::: "memory"); \
    __builtin_amdgcn_s_barrier();                            \
    __builtin_amdgcn_sched_barrier(0);                       \
  } while (0)
#define BAR_VM0_L()                                          \
  do {                                                       \
    asm volatile("s_waitcnt vmcnt(0) lgkmcnt(0)" ::: "memory"); \
    __builtin_amdgcn_s_barrier();                            \
    __builtin_amdgcn_sched_barrier(0);                       \
  } while (0)
#define BAR_ALL()                                            \
  do {                                                       \
    asm volatile("s_waitcnt vmcnt(0) lgkmcnt(0)" ::: "memory"); \
    __builtin_amdgcn_s_barrier();                            \
    __builtin_amdgcn_sched_barrier(0);                       \
  } while (0)

// ---------------- weight conversion: coalesced LDS transpose (r16) ----------------

__global__ __launch_bounds__(256) void conv_w_kernel(const float* __restrict__ Wh,
                                                     const float* __restrict__ Wl,
                                                     const float* __restrict__ Wg,
                                                     const float* __restrict__ Wm,
                                                     short* __restrict__ Wt) {
  __shared__ float lds[64][65];
  int w = blockIdx.x >> 6, tile = blockIdx.x & 63;
  int tk = (tile >> 3) * 64, tn = (tile & 7) * 64;
  const float* W = (w == 0) ? Wh : (w == 1) ? Wl : (w == 2) ? Wg : Wm;
  int tid = threadIdx.x;

  int rr = tid >> 4, cc4 = (tid & 15) * 4;
#pragma unroll
  for (int p = 0; p < 4; ++p) {
    int row = rr + p * 16;
    float4 v = *(const float4*)&W[(size_t)(tk + row) * 512 + tn + cc4];
    lds[row][cc4] = v.x; lds[row][cc4 + 1] = v.y;
    lds[row][cc4 + 2] = v.z; lds[row][cc4 + 3] = v.w;
  }
  __syncthreads();

  int k8 = (tid & 7) * 8;
#pragma unroll
  for (int p = 0; p < 2; ++p) {
    int n = (tid >> 3) + p * 32;
    s16x8 o;
#pragma unroll
    for (int j = 0; j < 8; ++j) o[j] = f2h(lds[k8 + j][n]);
    *(s16x8*)&Wt[(size_t)w * 262144 + (size_t)(tn + n) * 512 + tk + k8] = o;
  }
}

// ---------------- fused cvt + 3-way MLP GEMM (pipelined, r15/r16) ----------------

__global__ __launch_bounds__(256) void mlp3_kernel(const float* __restrict__ x,
                                                   const short* __restrict__ Wt_all,
                                                   const float* __restrict__ bh,
                                                   const float* __restrict__ bl,
                                                   const float* __restrict__ bg,
                                                   short* __restrict__ h,
                                                   short* __restrict__ l,
                                                   short* __restrict__ gT) {
  int z = blockIdx.z;
  const short* Wt = Wt_all + z * 262144;
  const float* bias = (z == 0) ? bh : (z == 1) ? bl : bg;

  __shared__ __align__(16) short abuf[2][4096];
  __shared__ __align__(16) short bbuf[3][4096];
  int tid = threadIdx.x, lane = tid & 63, w = tid >> 6;
  int wm = w >> 1, wn = w & 1;
  int bm = blockIdx.x * 128, bn = blockIdx.y * 128;
  int rx = lane & 15, g = lane >> 4;

  auto stageB = [&](int t) {
    int k0 = t * 32;
    short* bd = &bbuf[t % 3][0];
    int srow = lane >> 2;
    int scol = ((lane & 3) ^ ((lane >> 3) & 3)) * 8;
#pragma unroll
    for (int j = 0; j < 2; ++j) {
      int wl = w * 2 + j;
      int row = wl * 16 + srow;
      gload16(Wt + (size_t)(bn + row) * 512 + k0 + scol, bd + wl * 512 + lane * 8);
    }
  };
  auto loadA = [&](int t, s16x8 av[2]) {
#pragma unroll
    for (int it = 0; it < 2; ++it) {
      int c = tid + it * 256;
      int row = c >> 2, col8 = (c & 3) * 8;
      size_t base = (size_t)(bm + row) * 512 + t * 32 + col8;
      float4 x0 = *(const float4*)&x[base];
      float4 x1 = *(const float4*)&x[base + 4];
      s16x8 v;
      v[0] = f2h(x0.x); v[1] = f2h(x0.y); v[2] = f2h(x0.z); v[3] = f2h(x0.w);
      v[4] = f2h(x1.x); v[5] = f2h(x1.y); v[6] = f2h(x1.z); v[7] = f2h(x1.w);
      av[it] = v;
    }
  };
  auto writeA = [&](int t, s16x8 av[2]) {
    short* ad = &abuf[t & 1][0];
#pragma unroll
    for (int it = 0; it < 2; ++it) {
      int c = tid + it * 256;
      int row = c >> 2;
      int chunk_p = (c & 3) ^ ((row >> 1) & 3);
      *(s16x8*)&ad[row * 32 + chunk_p * 8] = av[it];
    }
  };

  f32x4 acc[4][4];
#pragma unroll
  for (int mi = 0; mi < 4; ++mi)
#pragma unroll
    for (int ni = 0; ni < 4; ++ni) acc[mi][ni] = (f32x4){0.f, 0.f, 0.f, 0.f};

  s16x8 av[2];
  loadA(0, av);
  stageB(0); stageB(1);
  writeA(0, av);
  BAR_KEEP2_L();

  int foff = rx * 32 + ((g ^ ((rx >> 1) & 3)) << 3);

  for (int t = 0; t < 16; ++t) {
    if (t < 15) loadA(t + 1, av);
    if (t < 14) stageB(t + 2);
    const short* ab = &abuf[t & 1][0];
    const short* bb = &bbuf[t % 3][0];
    f16x8 af[4], bfr[4];
#pragma unroll
    for (int mi = 0; mi < 4; ++mi)
      af[mi] = *(const f16x8*)&ab[(wm * 64 + mi * 16) * 32 + foff];
#pragma unroll
    for (int ni = 0; ni < 4; ++ni)
      bfr[ni] = *(const f16x8*)&bb[(wn * 64 + ni * 16) * 32 + foff];
#pragma unroll
    for (int mi = 0; mi < 4; ++mi)
#pragma unroll
      for (int ni = 0; ni < 4; ++ni) acc[mi][ni] = MFMA(af[mi], bfr[ni], acc[mi][ni]);
    if (t < 15) writeA(t + 1, av);
    if (t < 14) BAR_KEEP2_L();
    else if (t == 14) BAR_ALL();
  }

#pragma unroll
  for (int mi = 0; mi < 4; ++mi)
#pragma unroll
    for (int ni = 0; ni < 4; ++ni) {
      int col = bn + wn * 64 + ni * 16 + rx;
      float bv = bias[col];
#pragma unroll
      for (int r = 0; r < 4; ++r) {
        int row = bm + wm * 64 + mi * 16 + g * 4 + r;
        float v = fmaxf(acc[mi][ni][r] + bv, 0.0f);
        short o = f2h(v);
        if (z == 0) h[(size_t)row * 512 + col] = o;
        else if (z == 1) l[(size_t)row * 512 + col] = o;
        else {
          int bb2 = row >> 11, mm = row & 2047;
          gT[((size_t)bb2 * 512 + col) * 2048 + mm] = o;
        }
      }
    }
}

// ---------------- flash attention, split-K, wave-pair D-split ----------------
// 256 blocks x 512 threads. 8 waves = 4 pairs x 32 q; wave dh owns D-half.
// Partial QK^T per D-half; partials exchanged via sbuf (dbuf); PV on D-half.

__global__ __launch_bounds__(512, 1) void attn_split_kernel(
    const short* __restrict__ lmat, const short* __restrict__ hmat,
    const short* __restrict__ gT,
    short* __restrict__ OA, short* __restrict__ OB,
    float2* __restrict__ mlA, float2* __restrict__ mlB) {
  __shared__ __align__(16) short kbuf[3][8192];      // [16 keys][512], 48KB
  __shared__ __align__(16) short gbuf[2][8192];      // [512 c][16 keys], 32KB
  __shared__ __align__(16) f32x4 sbuf[2][8][2][64];  // partial S^T, 32KB
  int tid = threadIdx.x, lane = tid & 63, w = tid >> 6;  // w in 0..7
  int b = blockIdx.x & 7;
  int idx = blockIdx.x >> 3;        // 0..31
  int qt = idx >> 1, sp = idx & 1;
  int p = w >> 1, dh = w & 1;
  int q0 = qt * 128 + p * 32;
  int dbase = dh * 256;
  int keybase = sp * 1024;
  const short* lb = lmat + (size_t)b * 2048 * 512;
  const short* hb = hmat + (size_t)b * 2048 * 512;
  const short* gb = gT + (size_t)b * 512 * 2048;
  short* Op = sp ? OB : OA;
  float2* ml = sp ? mlB : mlA;

  int r0 = lane & 15, g = lane >> 4;
  int qA = q0 + r0, qB = q0 + 16 + r0;

  // Q fragments for this wave's D-half only: 8 k-chunks x 2 q-cols = 64 VGPR
  f16x8 qf[8][2];
#pragma unroll
  for (int kc = 0; kc < 8; ++kc) {
    qf[kc][0] = *(const f16x8*)&lb[(size_t)qA * 512 + dbase + kc * 32 + g * 8];
    qf[kc][1] = *(const f16x8*)&lb[(size_t)qB * 512 + dbase + kc * 32 + g * 8];
  }
  f32x4 accO[16][2];  // O^T D-half: 16 nf x 2 q-cols = 128 VGPR
#pragma unroll
  for (int i = 0; i < 16; ++i) {
    accO[i][0] = (f32x4){0.f, 0.f, 0.f, 0.f};
    accO[i][1] = (f32x4){0.f, 0.f, 0.f, 0.f};
  }
  float mrA = -3e38f, mrB = -3e38f, lsA = 0.f, lsB = 0.f;

  auto stageK = [&](int t) {
    int key0 = keybase + t * 16;
    short* kd = &kbuf[t % 3][0];
#pragma unroll
    for (int j = 0; j < 2; ++j) {
      int wl = w * 2 + j;
      gload16(hb + (size_t)(key0 + wl) * 512 + (((lane * 16) ^ ((wl & 7) << 4)) >> 1),
              kd + wl * 512);
    }
  };
  auto stageG = [&](int t) {
    int key0 = keybase + t * 16;
    short* gd = &gbuf[t & 1][0];
#pragma unroll
    for (int j = 0; j < 2; ++j) {
      int wl = w * 2 + j;
      int c = wl * 32 + (lane >> 1);
      int half = (lane & 1) ^ ((lane >> 3) & 1);
      gload16(gb + (size_t)c * 2048 + key0 + half * 8, gd + wl * 512);
    }
  };
  // partial QK^T over this wave's D-half, for both q-cols; writes to sbuf
  auto QKp = [&](int t) {
    const short* kb = &kbuf[t % 3][0];
    f32x4 s0 = {0.f, 0.f, 0.f, 0.f}, s1 = {0.f, 0.f, 0.f, 0.f};
#pragma unroll
    for (int kc = 0; kc < 8; ++kc) {
      f16x8 kf = *(const f16x8*)&kb[(r0 * 512 + dbase + kc * 32 + g * 8) ^
                                    ((r0 & 7) << 3)];
      s0 = MFMA(kf, qf[kc][0], s0);
      s1 = MFMA(kf, qf[kc][1], s1);
    }
    sbuf[t & 1][w][0][lane] = s0;
    sbuf[t & 1][w][1][lane] = s1;
  };

  // prologue: K0,K1,G0 drained; K2 in flight; partial S(0) exchanged
  stageK(0); stageK(1); stageG(0); stageK(2);
  BAR_KEEP2();
  __builtin_amdgcn_s_setprio(1);
  QKp(0);
  __builtin_amdgcn_s_setprio(0);
  BAR_KEEP2_L();   // flush S(0) writes; K(2) stays in flight

  int goff = (dbase + r0) * 16 + (((g >> 1) ^ ((r0 >> 2) & 1)) << 3) + ((g & 1) << 2);

  for (int t = 0; t < 64; ++t) {
    if (t < 63) stageG(t + 1);
    if (t < 61) stageK(t + 3);

    if (t < 63) {
      __builtin_amdgcn_s_setprio(1);
      QKp(t + 1);   // reads kbuf[(t+1)%3] (drained), writes sbuf[(t+1)&1][w]
      __builtin_amdgcn_s_setprio(0);
    }

    // ---- full S(t) = own partial + partner partial ----
    f32x4 o0 = sbuf[t & 1][w][0][lane] + sbuf[t & 1][w ^ 1][0][lane];
    f32x4 o1 = sbuf[t & 1][w][1][lane] + sbuf[t & 1][w ^ 1][1][lane];

    // ---- softmax(t), both q-cols; lane owns 4 keys per col ----
    float mA = fmaxf(fmaxf(o0[0], o0[1]), fmaxf(o0[2], o0[3]));
    float mB = fmaxf(fmaxf(o1[0], o1[1]), fmaxf(o1[2], o1[3]));
    mA = fmaxf(mA, __shfl_xor(mA, 16)); mA = fmaxf(mA, __shfl_xor(mA, 32));
    mB = fmaxf(mB, __shfl_xor(mB, 16)); mB = fmaxf(mB, __shfl_xor(mB, 32));
    bool ok = (mA <= mrA + 8.0f) && (mB <= mrB + 8.0f);  // defer-max THR=8
    if (!__all((int)ok)) {
      float nA = fmaxf(mrA, mA), nB = fmaxf(mrB, mB);
      float sA = __expf(mrA - nA), sB = __expf(mrB - nB);
      mrA = nA; mrB = nB;
      lsA *= sA; lsB *= sB;
#pragma unroll
      for (int nf = 0; nf < 16; ++nf) { accO[nf][0] *= sA; accO[nf][1] *= sB; }
    }
    float a0 = __expf(o0[0] - mrA), a1 = __expf(o0[1] - mrA);
    float a2 = __expf(o0[2] - mrA), a3 = __expf(o0[3] - mrA);
    float b0 = __expf(o1[0] - mrB), b1 = __expf(o1[1] - mrB);
    float b2 = __expf(o1[2] - mrB), b3 = __expf(o1[3] - mrB);
    lsA += (a0 + a1) + (a2 + a3);
    lsB += (b0 + b1) + (b2 + b3);

    u32x2 pwA = {pk2h(a0, a1), pk2h(a2, a3)};
    u32x2 pwB = {pk2h(b0, b1), pk2h(b2, b3)};
    f16x4 pfA = __builtin_bit_cast(f16x4, pwA);
    f16x4 pfB = __builtin_bit_cast(f16x4, pwB);

    // ---- PV(t) on this wave's D-half: 16 G-frags x 2 q-cols ----
    const short* gp = &gbuf[t & 1][goff];
    __builtin_amdgcn_s_setprio(1);
#pragma unroll
    for (int nf = 0; nf < 16; ++nf) {
      f16x4 gf = *(const f16x4*)&gp[nf * 256];
      accO[nf][0] = MFMA16(gf, pfA, accO[nf][0]);
      accO[nf][1] = MFMA16(gf, pfB, accO[nf][1]);
    }
    __builtin_amdgcn_s_setprio(0);

    if (t < 61) BAR_KEEP2_L(); else BAR_VM0_L();
  }

  // ---- epilogue: reduce denominators, store normalized O (D-half) ----
  lsA += __shfl_xor(lsA, 16); lsA += __shfl_xor(lsA, 32);
  lsB += __shfl_xor(lsB, 16); lsB += __shfl_xor(lsB, 32);
  float invA = 1.0f / lsA, invB = 1.0f / lsB;
#pragma unroll
  for (int nf = 0; nf < 16; ++nf) {
    int col = dbase + nf * 16 + g * 4;
    s16x4 oA4, oB4;
    oA4[0] = f2h(accO[nf][0][0] * invA); oA4[1] = f2h(accO[nf][0][1] * invA);
    oA4[2] = f2h(accO[nf][0][2] * invA); oA4[3] = f2h(accO[nf][0][3] * invA);
    oB4[0] = f2h(accO[nf][1][0] * invB); oB4[1] = f2h(accO[nf][1][1] * invB);
    oB4[2] = f2h(accO[nf][1][2] * invB); oB4[3] = f2h(accO[nf][1][3] * invB);
    *(s16x4*)&Op[((size_t)b * 2048 + qA) * 512 + col] = oA4;
    *(s16x4*)&Op[((size_t)b * 2048 + qB) * 512 + col] = oB4;
  }
  if (dh == 0 && g == 0) {
    ml[(size_t)b * 2048 + qA] = make_float2(mrA, lsA);
    ml[(size_t)b * 2048 + qB] = make_float2(mrB, lsB);
  }
}

// ---------------- fused combine + final GEMM (pipelined, r13, frozen) ----------------

__global__ __launch_bounds__(256) void final_gemm_kernel(
    const short* __restrict__ OA, const short* __restrict__ OB,
    const float2* __restrict__ mlA, const float2* __restrict__ mlB,
    const float* __restrict__ x, const short* __restrict__ Wt,
    const float* __restrict__ bias, float* __restrict__ out) {
  __shared__ __align__(16) short abuf[2][4096];
  __shared__ __align__(16) short bbuf[3][4096];
  int tid = threadIdx.x, lane = tid & 63, w = tid >> 6;
  int wm = w >> 1, wn = w & 1;
  int bm = blockIdx.x * 128, bn = blockIdx.y * 128;
  int rx = lane & 15, g = lane >> 4;

  float wgt[2][2];
#pragma unroll
  for (int it = 0; it < 2; ++it) {
    int row = (tid >> 2) + it * 64;
    float2 a2 = mlA[bm + row], b2 = mlB[bm + row];
    float ms = fmaxf(a2.x, b2.x);
    float wA = __expf(a2.x - ms) * a2.y;
    float wB = __expf(b2.x - ms) * b2.y;
    float winv = 1.0f / (wA + wB);
    wgt[it][0] = wA * winv;
    wgt[it][1] = wB * winv;
  }

  auto stageB = [&](int t) {
    int k0 = t * 32;
    short* bd = &bbuf[t % 3][0];
    int srow = lane >> 2;
    int scol = ((lane & 3) ^ ((lane >> 3) & 3)) * 8;
#pragma unroll
    for (int j = 0; j < 2; ++j) {
      int wl = w * 2 + j;
      int row = wl * 16 + srow;
      gload16(Wt + (size_t)(bn + row) * 512 + k0 + scol, bd + wl * 512 + lane * 8);
    }
  };
  auto loadA = [&](int t, s16x8 av[2]) {
#pragma unroll
    for (int it = 0; it < 2; ++it) {
      int c = tid + it * 256;
      int row = c >> 2, col8 = (c & 3) * 8;
      size_t base = (size_t)(bm + row) * 512 + t * 32 + col8;
      f16x8 oa = *(const f16x8*)&OA[base];
      f16x8 ob = *(const f16x8*)&OB[base];
      float4 x0 = *(const float4*)&x[base];
      float4 x1 = *(const float4*)&x[base + 4];
      float wA = wgt[it][0], wB = wgt[it][1];
      s16x8 v;
      v[0] = f2h((float)oa[0] * wA + (float)ob[0] * wB + x0.x);
      v[1] = f2h((float)oa[1] * wA + (float)ob[1] * wB + x0.y);
      v[2] = f2h((float)oa[2] * wA + (float)ob[2] * wB + x0.z);
      v[3] = f2h((float)oa[3] * wA + (float)ob[3] * wB + x0.w);
      v[4] = f2h((float)oa[4] * wA + (float)ob[4] * wB + x1.x);
      v[5] = f2h((float)oa[5] * wA + (float)ob[5] * wB + x1.y);
      v[6] = f2h((float)oa[6] * wA + (float)ob[6] * wB + x1.z);
      v[7] = f2h((float)oa[7] * wA + (float)ob[7] * wB + x1.w);
      av[it] = v;
    }
  };
  auto writeA = [&](int t, s16x8 av[2]) {
    short* ad = &abuf[t & 1][0];
#pragma unroll
    for (int it = 0; it < 2; ++it) {
      int c = tid + it * 256;
      int row = c >> 2;
      int chunk_p = (c & 3) ^ ((row >> 1) & 3);
      *(s16x8*)&ad[row * 32 + chunk_p * 8] = av[it];
    }
  };

  f32x4 acc[4][4];
#pragma unroll
  for (int mi = 0; mi < 4; ++mi)
#pragma unroll
    for (int ni = 0; ni < 4; ++ni) acc[mi][ni] = (f32x4){0.f, 0.f, 0.f, 0.f};

  s16x8 av[2];
  loadA(0, av);
  stageB(0); stageB(1);
  writeA(0, av);
  BAR_KEEP4_L();

  int foff = rx * 32 + ((g ^ ((rx >> 1) & 3)) << 3);

  for (int t = 0; t < 16; ++t) {
    if (t < 15) loadA(t + 1, av);
    if (t < 14) stageB(t + 2);
    const short* ab = &abuf[t & 1][0];
    const short* bb = &bbuf[t % 3][0];
    f16x8 af[4], bfr[4];
#pragma unroll
    for (int mi = 0; mi < 4; ++mi)
      af[mi] = *(const f16x8*)&ab[(wm * 64 + mi * 16) * 32 + foff];
#pragma unroll
    for (int ni = 0; ni < 4; ++ni)
      bfr[ni] = *(const f16x8*)&bb[(wn * 64 + ni * 16) * 32 + foff];
#pragma unroll
    for (int mi = 0; mi < 4; ++mi)
#pragma unroll
      for (int ni = 0; ni < 4; ++ni) acc[mi][ni] = MFMA(af[mi], bfr[ni], acc[mi][ni]);
    if (t < 15) writeA(t + 1, av);
    if (t < 14) BAR_KEEP4_L();
    else if (t == 14) BAR_ALL();
  }

#pragma unroll
  for (int mi = 0; mi < 4; ++mi)
#pragma unroll
    for (int ni = 0; ni < 4; ++ni) {
      int col = bn + wn * 64 + ni * 16 + rx;
      float bv = bias[col];
#pragma unroll
      for (int r = 0; r < 4; ++r) {
        int row = bm + wm * 64 + mi * 16 + g * 4 + r;
        out[(size_t)row * 512 + col] = fmaxf(acc[mi][ni][r] + bv, 0.0f);
      }
    }
}

// ---------------- host launch ----------------

extern "C" void kernel_launch(void* const* d_in, const int* in_sizes, int n_in,
                              void* d_out, int out_size, void* d_ws, size_t ws_size,
                              hipStream_t stream) {
  const float* x  = (const float*)d_in[0];
  const float* Wh = (const float*)d_in[1];
  const float* bh = (const float*)d_in[2];
  const float* Wl = (const float*)d_in[3];
  const float* bl = (const float*)d_in[4];
  const float* Wg = (const float*)d_in[5];
  const float* bg = (const float*)d_in[6];
  const float* Wm = (const float*)d_in[7];
  const float* bm = (const float*)d_in[8];

  char* ws = (char*)d_ws;
  const size_t SZ = 16777216;
  short*  OA  = (short*)(ws + 0 * SZ);
  short*  h   = (short*)(ws + 1 * SZ);
  short*  l   = (short*)(ws + 2 * SZ);
  short*  gT  = (short*)(ws + 3 * SZ);
  short*  OB  = (short*)(ws + 4 * SZ);
  short*  Wt  = (short*)(ws + 5 * SZ);   // 2 MB
  float2* mlA = (float2*)(ws + 5 * SZ + 2097152);            // 128 KB
  float2* mlB = (float2*)(ws + 5 * SZ + 2097152 + 131072);   // 128 KB

  conv_w_kernel<<<256, 256, 0, stream>>>(Wh, Wl, Wg, Wm, Wt);
  mlp3_kernel<<<dim3(128, 4, 3), 256, 0, stream>>>(x, Wt, bh, bl, bg, h, l, gT);
  attn_split_kernel<<<256, 512, 0, stream>>>(l, h, gT, OA, OB, mlA, mlB);
  final_gemm_kernel<<<dim3(128, 4), 256, 0, stream>>>(OA, OB, mlA, mlB, x,
                                                      Wt + 3 * 262144, bm,
                                                      (float*)d_out);
}

// Round 18
// 230.481 us; speedup vs baseline: 1.0555x; 1.0555x over previous
//
#include <hip/hip_runtime.h>

// B=8, N=2048, C=512. Flash attention + fp16 MFMA pipeline.
// r18 = r16 locked in (best verified: 230.3 µs; r17's D-split exchange
// regressed and is reverted). Design point is three-way saturated:
// attn LDS pipe ~85-90% busy; regs 252/256 (2 waves/SIMD boundary);
// grid = 1 block/CU at 80KB LDS. Remaining conflicts are benign 2-way.
// ws: [0]=OA [1]=h [2]=l [3]=gT [4]=OB [5]=Wt(2MB)+ml(256KB)

typedef __attribute__((ext_vector_type(4))) float f32x4;
typedef __attribute__((ext_vector_type(8))) short s16x8;      // fp16 bit-patterns
typedef __attribute__((ext_vector_type(4))) short s16x4;
typedef __attribute__((ext_vector_type(8))) _Float16 f16x8;   // MFMA operands
typedef __attribute__((ext_vector_type(4))) _Float16 f16x4;
typedef __attribute__((ext_vector_type(2))) unsigned u32x2;

typedef unsigned int u32;
typedef __attribute__((address_space(1))) const u32 gu32;
typedef __attribute__((address_space(3))) u32 lu32;

__device__ __forceinline__ void gload16(const short* g, short* l) {
  __builtin_amdgcn_global_load_lds((gu32*)g, (lu32*)l, 16, 0, 0);
}

__device__ __forceinline__ short f2h(float f) {
  _Float16 h = (_Float16)f;
  return __builtin_bit_cast(short, h);
}

__device__ __forceinline__ unsigned pk2h(float a, float b) {
  return __builtin_bit_cast(unsigned, __builtin_amdgcn_cvt_pkrtz(a, b));
}

#define MFMA(a, b, c) __builtin_amdgcn_mfma_f32_16x16x32_f16(a, b, c, 0, 0, 0)
#define MFMA16(a, b, c) __builtin_amdgcn_mfma_f32_16x16x16f16(a, b, c, 0, 0, 0)

#define BAR_KEEP2()                                          \
  do {                                                       \
    asm volatile("s_waitcnt vmcnt(2)" ::: "memory");         \
    __builtin_amdgcn_s_barrier();                            \
    __builtin_amdgcn_sched_barrier(0);                       \
  } while (0)
#define BAR_KEEP2_L()                                        \
  do {                                                       \
    asm volatile("s_waitcnt vmcnt(2) lgkmcnt(0)" ::: "memory"); \
    __builtin_amdgcn_s_barrier();                            \
    __builtin_amdgcn_sched_barrier(0);                       \
  } while (0)
#define BAR_KEEP4_L()                                        \
  do {                                                       \
    asm volatile("s_waitcnt vmcnt(4) lgkmcnt(0)" ::: "memory"); \
    __builtin_amdgcn_s_barrier();                            \
    __builtin_amdgcn_sched_barrier(0);                       \
  } while (0)
#define BAR_VM0()                                            \
  do {                                                       \
    asm volatile("s_waitcnt vmcnt(0)" ::: "memory");         \
    __builtin_amdgcn_s_barrier();                            \
    __builtin_amdgcn_sched_barrier(0);                       \
  } while (0)
#define BAR_ALL()                                            \
  do {                                                       \
    asm volatile("s_waitcnt vmcnt(0) lgkmcnt(0)" ::: "memory"); \
    __builtin_amdgcn_s_barrier();                            \
    __builtin_amdgcn_sched_barrier(0);                       \
  } while (0)

// ---------------- weight conversion: coalesced LDS transpose ----------------

__global__ __launch_bounds__(256) void conv_w_kernel(const float* __restrict__ Wh,
                                                     const float* __restrict__ Wl,
                                                     const float* __restrict__ Wg,
                                                     const float* __restrict__ Wm,
                                                     short* __restrict__ Wt) {
  __shared__ float lds[64][65];
  int w = blockIdx.x >> 6, tile = blockIdx.x & 63;
  int tk = (tile >> 3) * 64, tn = (tile & 7) * 64;
  const float* W = (w == 0) ? Wh : (w == 1) ? Wl : (w == 2) ? Wg : Wm;
  int tid = threadIdx.x;

  int rr = tid >> 4, cc4 = (tid & 15) * 4;
#pragma unroll
  for (int p = 0; p < 4; ++p) {
    int row = rr + p * 16;
    float4 v = *(const float4*)&W[(size_t)(tk + row) * 512 + tn + cc4];
    lds[row][cc4] = v.x; lds[row][cc4 + 1] = v.y;
    lds[row][cc4 + 2] = v.z; lds[row][cc4 + 3] = v.w;
  }
  __syncthreads();

  int k8 = (tid & 7) * 8;
#pragma unroll
  for (int p = 0; p < 2; ++p) {
    int n = (tid >> 3) + p * 32;
    s16x8 o;
#pragma unroll
    for (int j = 0; j < 8; ++j) o[j] = f2h(lds[k8 + j][n]);
    *(s16x8*)&Wt[(size_t)w * 262144 + (size_t)(tn + n) * 512 + tk + k8] = o;
  }
}

// ---------------- fused cvt + 3-way MLP GEMM (pipelined) ----------------

__global__ __launch_bounds__(256) void mlp3_kernel(const float* __restrict__ x,
                                                   const short* __restrict__ Wt_all,
                                                   const float* __restrict__ bh,
                                                   const float* __restrict__ bl,
                                                   const float* __restrict__ bg,
                                                   short* __restrict__ h,
                                                   short* __restrict__ l,
                                                   short* __restrict__ gT) {
  int z = blockIdx.z;
  const short* Wt = Wt_all + z * 262144;
  const float* bias = (z == 0) ? bh : (z == 1) ? bl : bg;

  __shared__ __align__(16) short abuf[2][4096];
  __shared__ __align__(16) short bbuf[3][4096];
  int tid = threadIdx.x, lane = tid & 63, w = tid >> 6;
  int wm = w >> 1, wn = w & 1;
  int bm = blockIdx.x * 128, bn = blockIdx.y * 128;
  int rx = lane & 15, g = lane >> 4;

  auto stageB = [&](int t) {
    int k0 = t * 32;
    short* bd = &bbuf[t % 3][0];
    int srow = lane >> 2;
    int scol = ((lane & 3) ^ ((lane >> 3) & 3)) * 8;
#pragma unroll
    for (int j = 0; j < 2; ++j) {
      int wl = w * 2 + j;
      int row = wl * 16 + srow;
      gload16(Wt + (size_t)(bn + row) * 512 + k0 + scol, bd + wl * 512 + lane * 8);
    }
  };
  auto loadA = [&](int t, s16x8 av[2]) {
#pragma unroll
    for (int it = 0; it < 2; ++it) {
      int c = tid + it * 256;
      int row = c >> 2, col8 = (c & 3) * 8;
      size_t base = (size_t)(bm + row) * 512 + t * 32 + col8;
      float4 x0 = *(const float4*)&x[base];
      float4 x1 = *(const float4*)&x[base + 4];
      s16x8 v;
      v[0] = f2h(x0.x); v[1] = f2h(x0.y); v[2] = f2h(x0.z); v[3] = f2h(x0.w);
      v[4] = f2h(x1.x); v[5] = f2h(x1.y); v[6] = f2h(x1.z); v[7] = f2h(x1.w);
      av[it] = v;
    }
  };
  auto writeA = [&](int t, s16x8 av[2]) {
    short* ad = &abuf[t & 1][0];
#pragma unroll
    for (int it = 0; it < 2; ++it) {
      int c = tid + it * 256;
      int row = c >> 2;
      int chunk_p = (c & 3) ^ ((row >> 1) & 3);
      *(s16x8*)&ad[row * 32 + chunk_p * 8] = av[it];
    }
  };

  f32x4 acc[4][4];
#pragma unroll
  for (int mi = 0; mi < 4; ++mi)
#pragma unroll
    for (int ni = 0; ni < 4; ++ni) acc[mi][ni] = (f32x4){0.f, 0.f, 0.f, 0.f};

  s16x8 av[2];
  loadA(0, av);
  stageB(0); stageB(1);
  writeA(0, av);
  BAR_KEEP2_L();

  int foff = rx * 32 + ((g ^ ((rx >> 1) & 3)) << 3);

  for (int t = 0; t < 16; ++t) {
    if (t < 15) loadA(t + 1, av);
    if (t < 14) stageB(t + 2);
    const short* ab = &abuf[t & 1][0];
    const short* bb = &bbuf[t % 3][0];
    f16x8 af[4], bfr[4];
#pragma unroll
    for (int mi = 0; mi < 4; ++mi)
      af[mi] = *(const f16x8*)&ab[(wm * 64 + mi * 16) * 32 + foff];
#pragma unroll
    for (int ni = 0; ni < 4; ++ni)
      bfr[ni] = *(const f16x8*)&bb[(wn * 64 + ni * 16) * 32 + foff];
#pragma unroll
    for (int mi = 0; mi < 4; ++mi)
#pragma unroll
      for (int ni = 0; ni < 4; ++ni) acc[mi][ni] = MFMA(af[mi], bfr[ni], acc[mi][ni]);
    if (t < 15) writeA(t + 1, av);
    if (t < 14) BAR_KEEP2_L();
    else if (t == 14) BAR_ALL();
  }

#pragma unroll
  for (int mi = 0; mi < 4; ++mi)
#pragma unroll
    for (int ni = 0; ni < 4; ++ni) {
      int col = bn + wn * 64 + ni * 16 + rx;
      float bv = bias[col];
#pragma unroll
      for (int r = 0; r < 4; ++r) {
        int row = bm + wm * 64 + mi * 16 + g * 4 + r;
        float v = fmaxf(acc[mi][ni][r] + bv, 0.0f);
        short o = f2h(v);
        if (z == 0) h[(size_t)row * 512 + col] = o;
        else if (z == 1) l[(size_t)row * 512 + col] = o;
        else {
          int bb2 = row >> 11, mm = row & 2047;
          gT[((size_t)bb2 * 512 + col) * 2048 + mm] = o;
        }
      }
    }
}

// ---------------- flash attention, split-K (r12 winner, frozen) ----------------

__global__ __launch_bounds__(512, 1) void attn_split_kernel(
    const short* __restrict__ lmat, const short* __restrict__ hmat,
    const short* __restrict__ gT,
    short* __restrict__ OA, short* __restrict__ OB,
    float2* __restrict__ mlA, float2* __restrict__ mlB) {
  __shared__ __align__(16) short kbuf[3][8192];  // 48KB
  __shared__ __align__(16) short gbuf[2][8192];  // 32KB
  int tid = threadIdx.x, lane = tid & 63, w = tid >> 6;  // w in 0..7
  int b = blockIdx.x & 7;
  int idx = blockIdx.x >> 3;
  int qt = idx >> 1, sp = idx & 1;
  int q0 = qt * 128 + w * 16;
  int keybase = sp * 1024;
  const short* lb = lmat + (size_t)b * 2048 * 512;
  const short* hb = hmat + (size_t)b * 2048 * 512;
  const short* gb = gT + (size_t)b * 512 * 2048;
  short* Op = sp ? OB : OA;
  float2* ml = sp ? mlB : mlA;

  int r0 = lane & 15, g = lane >> 4;

  f16x8 qf[16];
  {
    int q = q0 + r0;
#pragma unroll
    for (int ks = 0; ks < 16; ++ks)
      qf[ks] = *(const f16x8*)&lb[(size_t)q * 512 + ks * 32 + g * 8];
  }
  f32x4 accO[32];
#pragma unroll
  for (int i = 0; i < 32; ++i) accO[i] = (f32x4){0.f, 0.f, 0.f, 0.f};
  float mrun = -3e38f, lsumL = 0.f;

  auto stageK = [&](int t) {
    int key0 = keybase + t * 16;
    short* kd = &kbuf[t % 3][0];
#pragma unroll
    for (int j = 0; j < 2; ++j) {
      int wl = w * 2 + j;
      gload16(hb + (size_t)(key0 + wl) * 512 + (((lane * 16) ^ ((wl & 7) << 4)) >> 1),
              kd + wl * 512);
    }
  };
  auto stageG = [&](int t) {
    int key0 = keybase + t * 16;
    short* gd = &gbuf[t & 1][0];
#pragma unroll
    for (int j = 0; j < 2; ++j) {
      int wl = w * 2 + j;
      int c = wl * 32 + (lane >> 1);
      int half = (lane & 1) ^ ((lane >> 3) & 1);
      gload16(gb + (size_t)c * 2048 + key0 + half * 8, gd + wl * 512);
    }
  };
  auto QK = [&](int t, f32x4& o) {
    const short* kb = &kbuf[t % 3][0];
#pragma unroll
    for (int ks = 0; ks < 16; ++ks) {
      f16x8 kf = *(const f16x8*)&kb[(r0 * 512 + ks * 32 + g * 8) ^ ((r0 & 7) << 3)];
      o = MFMA(kf, qf[ks], o);
    }
  };

  stageK(0); stageK(1); stageG(0); stageK(2);
  BAR_KEEP2();
  f32x4 sc = {0.f, 0.f, 0.f, 0.f};
  QK(0, sc);
  BAR_KEEP2();

  int goff = r0 * 16 + (((g >> 1) ^ ((r0 >> 2) & 1)) << 3) + ((g & 1) << 2);

  for (int t = 0; t < 64; ++t) {
    if (t < 63) stageG(t + 1);
    if (t < 61) stageK(t + 3);

    f32x4 sn = {0.f, 0.f, 0.f, 0.f};
    if (t < 63) {
      __builtin_amdgcn_s_setprio(1);
      QK(t + 1, sn);
      __builtin_amdgcn_s_setprio(0);
    }

    float m2 = fmaxf(fmaxf(sc[0], sc[1]), fmaxf(sc[2], sc[3]));
    m2 = fmaxf(m2, __shfl_xor(m2, 16));
    m2 = fmaxf(m2, __shfl_xor(m2, 32));
    bool ok = (m2 <= mrun + 8.0f);
    if (!__all((int)ok)) {
      float mnew = fmaxf(mrun, m2);
      float s = __expf(mrun - mnew);
      mrun = mnew;
      lsumL *= s;
#pragma unroll
      for (int nf = 0; nf < 32; ++nf) accO[nf] *= s;
    }
    float p0 = __expf(sc[0] - mrun), p1 = __expf(sc[1] - mrun);
    float p2 = __expf(sc[2] - mrun), p3 = __expf(sc[3] - mrun);
    lsumL += (p0 + p1) + (p2 + p3);

    u32x2 pw = {pk2h(p0, p1), pk2h(p2, p3)};
    f16x4 pfrag = __builtin_bit_cast(f16x4, pw);

    const short* gp = &gbuf[t & 1][goff];
    __builtin_amdgcn_s_setprio(1);
#pragma unroll
    for (int nf = 0; nf < 32; ++nf) {
      f16x4 gf = *(const f16x4*)&gp[nf * 256];
      accO[nf] = MFMA16(gf, pfrag, accO[nf]);
    }
    __builtin_amdgcn_s_setprio(0);

    if (t < 61) BAR_KEEP2(); else BAR_VM0();
    sc = sn;
  }

  float ls = lsumL;
  ls += __shfl_xor(ls, 16);
  ls += __shfl_xor(ls, 32);
  float inv = 1.0f / ls;
  int q = q0 + r0;
#pragma unroll
  for (int nf = 0; nf < 32; ++nf) {
    s16x4 o;
    o[0] = f2h(accO[nf][0] * inv);
    o[1] = f2h(accO[nf][1] * inv);
    o[2] = f2h(accO[nf][2] * inv);
    o[3] = f2h(accO[nf][3] * inv);
    *(s16x4*)&Op[((size_t)b * 2048 + q) * 512 + nf * 16 + g * 4] = o;
  }
  if (g == 0) ml[(size_t)b * 2048 + q] = make_float2(mrun, ls);
}

// ---------------- fused combine + final GEMM (pipelined, frozen) ----------------

__global__ __launch_bounds__(256) void final_gemm_kernel(
    const short* __restrict__ OA, const short* __restrict__ OB,
    const float2* __restrict__ mlA, const float2* __restrict__ mlB,
    const float* __restrict__ x, const short* __restrict__ Wt,
    const float* __restrict__ bias, float* __restrict__ out) {
  __shared__ __align__(16) short abuf[2][4096];
  __shared__ __align__(16) short bbuf[3][4096];
  int tid = threadIdx.x, lane = tid & 63, w = tid >> 6;
  int wm = w >> 1, wn = w & 1;
  int bm = blockIdx.x * 128, bn = blockIdx.y * 128;
  int rx = lane & 15, g = lane >> 4;

  float wgt[2][2];
#pragma unroll
  for (int it = 0; it < 2; ++it) {
    int row = (tid >> 2) + it * 64;
    float2 a2 = mlA[bm + row], b2 = mlB[bm + row];
    float ms = fmaxf(a2.x, b2.x);
    float wA = __expf(a2.x - ms) * a2.y;
    float wB = __expf(b2.x - ms) * b2.y;
    float winv = 1.0f / (wA + wB);
    wgt[it][0] = wA * winv;
    wgt[it][1] = wB * winv;
  }

  auto stageB = [&](int t) {
    int k0 = t * 32;
    short* bd = &bbuf[t % 3][0];
    int srow = lane >> 2;
    int scol = ((lane & 3) ^ ((lane >> 3) & 3)) * 8;
#pragma unroll
    for (int j = 0; j < 2; ++j) {
      int wl = w * 2 + j;
      int row = wl * 16 + srow;
      gload16(Wt + (size_t)(bn + row) * 512 + k0 + scol, bd + wl * 512 + lane * 8);
    }
  };
  auto loadA = [&](int t, s16x8 av[2]) {
#pragma unroll
    for (int it = 0; it < 2; ++it) {
      int c = tid + it * 256;
      int row = c >> 2, col8 = (c & 3) * 8;
      size_t base = (size_t)(bm + row) * 512 + t * 32 + col8;
      f16x8 oa = *(const f16x8*)&OA[base];
      f16x8 ob = *(const f16x8*)&OB[base];
      float4 x0 = *(const float4*)&x[base];
      float4 x1 = *(const float4*)&x[base + 4];
      float wA = wgt[it][0], wB = wgt[it][1];
      s16x8 v;
      v[0] = f2h((float)oa[0] * wA + (float)ob[0] * wB + x0.x);
      v[1] = f2h((float)oa[1] * wA + (float)ob[1] * wB + x0.y);
      v[2] = f2h((float)oa[2] * wA + (float)ob[2] * wB + x0.z);
      v[3] = f2h((float)oa[3] * wA + (float)ob[3] * wB + x0.w);
      v[4] = f2h((float)oa[4] * wA + (float)ob[4] * wB + x1.x);
      v[5] = f2h((float)oa[5] * wA + (float)ob[5] * wB + x1.y);
      v[6] = f2h((float)oa[6] * wA + (float)ob[6] * wB + x1.z);
      v[7] = f2h((float)oa[7] * wA + (float)ob[7] * wB + x1.w);
      av[it] = v;
    }
  };
  auto writeA = [&](int t, s16x8 av[2]) {
    short* ad = &abuf[t & 1][0];
#pragma unroll
    for (int it = 0; it < 2; ++it) {
      int c = tid + it * 256;
      int row = c >> 2;
      int chunk_p = (c & 3) ^ ((row >> 1) & 3);
      *(s16x8*)&ad[row * 32 + chunk_p * 8] = av[it];
    }
  };

  f32x4 acc[4][4];
#pragma unroll
  for (int mi = 0; mi < 4; ++mi)
#pragma unroll
    for (int ni = 0; ni < 4; ++ni) acc[mi][ni] = (f32x4){0.f, 0.f, 0.f, 0.f};

  s16x8 av[2];
  loadA(0, av);
  stageB(0); stageB(1);
  writeA(0, av);
  BAR_KEEP4_L();

  int foff = rx * 32 + ((g ^ ((rx >> 1) & 3)) << 3);

  for (int t = 0; t < 16; ++t) {
    if (t < 15) loadA(t + 1, av);
    if (t < 14) stageB(t + 2);
    const short* ab = &abuf[t & 1][0];
    const short* bb = &bbuf[t % 3][0];
    f16x8 af[4], bfr[4];
#pragma unroll
    for (int mi = 0; mi < 4; ++mi)
      af[mi] = *(const f16x8*)&ab[(wm * 64 + mi * 16) * 32 + foff];
#pragma unroll
    for (int ni = 0; ni < 4; ++ni)
      bfr[ni] = *(const f16x8*)&bb[(wn * 64 + ni * 16) * 32 + foff];
#pragma unroll
    for (int mi = 0; mi < 4; ++mi)
#pragma unroll
      for (int ni = 0; ni < 4; ++ni) acc[mi][ni] = MFMA(af[mi], bfr[ni], acc[mi][ni]);
    if (t < 15) writeA(t + 1, av);
    if (t < 14) BAR_KEEP4_L();
    else if (t == 14) BAR_ALL();
  }

#pragma unroll
  for (int mi = 0; mi < 4; ++mi)
#pragma unroll
    for (int ni = 0; ni < 4; ++ni) {
      int col = bn + wn * 64 + ni * 16 + rx;
      float bv = bias[col];
#pragma unroll
      for (int r = 0; r < 4; ++r) {
        int row = bm + wm * 64 + mi * 16 + g * 4 + r;
        out[(size_t)row * 512 + col] = fmaxf(acc[mi][ni][r] + bv, 0.0f);
      }
    }
}

// ---------------- host launch ----------------

extern "C" void kernel_launch(void* const* d_in, const int* in_sizes, int n_in,
                              void* d_out, int out_size, void* d_ws, size_t ws_size,
                              hipStream_t stream) {
  const float* x  = (const float*)d_in[0];
  const float* Wh = (const float*)d_in[1];
  const float* bh = (const float*)d_in[2];
  const float* Wl = (const float*)d_in[3];
  const float* bl = (const float*)d_in[4];
  const float* Wg = (const float*)d_in[5];
  const float* bg = (const float*)d_in[6];
  const float* Wm = (const float*)d_in[7];
  const float* bm = (const float*)d_in[8];

  char* ws = (char*)d_ws;
  const size_t SZ = 16777216;
  short*  OA  = (short*)(ws + 0 * SZ);
  short*  h   = (short*)(ws + 1 * SZ);
  short*  l   = (short*)(ws + 2 * SZ);
  short*  gT  = (short*)(ws + 3 * SZ);
  short*  OB  = (short*)(ws + 4 * SZ);
  short*  Wt  = (short*)(ws + 5 * SZ);   // 2 MB
  float2* mlA = (float2*)(ws + 5 * SZ + 2097152);            // 128 KB
  float2* mlB = (float2*)(ws + 5 * SZ + 2097152 + 131072);   // 128 KB

  conv_w_kernel<<<256, 256, 0, stream>>>(Wh, Wl, Wg, Wm, Wt);
  mlp3_kernel<<<dim3(128, 4, 3), 256, 0, stream>>>(x, Wt, bh, bl, bg, h, l, gT);
  attn_split_kernel<<<256, 512, 0, stream>>>(l, h, gT, OA, OB, mlA, mlB);
  final_gemm_kernel<<<dim3(128, 4), 256, 0, stream>>>(OA, OB, mlA, mlB, x,
                                                      Wt + 3 * 262144, bm,
                                                      (float*)d_out);
}